// Round 1
// baseline (517.804 us; speedup 1.0000x reference)
//
#include <hip/hip_runtime.h>
#include <hip/hip_bf16.h>

typedef __bf16 bf16;
typedef __attribute__((ext_vector_type(8))) __bf16 bf16x8;
typedef __attribute__((ext_vector_type(4))) float f32x4;

#define B_ 8
#define N_ 1024
#define M_ 1024
#define D_ 512
#define H_ 8
#define DS_ 64
#define ROWS_ (B_ * N_)   // 8192

__device__ __forceinline__ f32x4 mfma16(bf16x8 a, bf16x8 b, f32x4 c) {
    return __builtin_amdgcn_mfma_f32_16x16x32_bf16(a, b, c, 0, 0, 0);
}

// ---------------- conversions ----------------
__global__ void cvt_bf16(const float* __restrict__ in, bf16* __restrict__ out, int n) {
    int i = blockIdx.x * 256 + threadIdx.x;
    if (i < n) out[i] = (bf16)in[i];
}

// Wt[n*512+k] = W[k*512+n], bf16
__global__ void wtrans(const float* __restrict__ W, bf16* __restrict__ Wt) {
    int i = blockIdx.x * 256 + threadIdx.x;   // i = n*512 + k
    int n = i >> 9, k = i & 511;
    Wt[i] = (bf16)W[k * 512 + n];
}

// Vt[((b*H+h)*64+d)*1024 + m] = V[(b*1024+m)*512 + h*64 + d]
__global__ void vtrans(const bf16* __restrict__ V, bf16* __restrict__ Vt) {
    int i = blockIdx.x * 256 + threadIdx.x;
    int m = i & 1023;
    int d = (i >> 10) & 63;
    int h = (i >> 16) & 7;
    int b = i >> 19;
    Vt[i] = V[((b << 10) + m) * 512 + h * 64 + d];
}

// ---------------- GEMM: C[M=8192,512] = A[8192,512](bf16) x Bt[n][k](bf16) ----------------
// MODE: 0 = fp32 out; 1 = bf16 out; 2 = fp32 out + bias; 3 = bf16 out + bias + relu
template <int MODE>
__global__ __launch_bounds__(256) void gemm_bt(const bf16* __restrict__ A,
                                               const bf16* __restrict__ Bt,
                                               const float* __restrict__ bias,
                                               void* __restrict__ Cout) {
    const int K = 512, NC = 512;
    int wave = threadIdx.x >> 6, lane = threadIdx.x & 63;
    int lr = lane & 15, q4 = lane >> 4;
    int row0 = blockIdx.x * 64 + wave * 16;
    int col0 = blockIdx.y * 64;
    const bf16* Ar = A + (size_t)(row0 + lr) * K + q4 * 8;
    f32x4 acc[4] = {{0.f,0.f,0.f,0.f},{0.f,0.f,0.f,0.f},{0.f,0.f,0.f,0.f},{0.f,0.f,0.f,0.f}};
    for (int k0 = 0; k0 < K; k0 += 32) {
        bf16x8 a = *reinterpret_cast<const bf16x8*>(Ar + k0);
#pragma unroll
        for (int nt = 0; nt < 4; ++nt) {
            bf16x8 b = *reinterpret_cast<const bf16x8*>(Bt + (size_t)(col0 + nt * 16 + lr) * K + k0 + q4 * 8);
            acc[nt] = mfma16(a, b, acc[nt]);
        }
    }
#pragma unroll
    for (int nt = 0; nt < 4; ++nt) {
        int col = col0 + nt * 16 + lr;
        float bv = (MODE >= 2) ? bias[col] : 0.0f;
#pragma unroll
        for (int r = 0; r < 4; ++r) {
            int row = row0 + q4 * 4 + r;
            float v = acc[nt][r] + bv;
            if (MODE == 3) v = fmaxf(v, 0.0f);
            if (MODE == 1 || MODE == 3)
                ((bf16*)Cout)[(size_t)row * NC + col] = (bf16)v;
            else
                ((float*)Cout)[(size_t)row * NC + col] = v;
        }
    }
}

// ---------------- attention ----------------
// grid: B*H*(N/16) = 4096 blocks of 64 threads (1 wave). Q,K: [b,n,h*64+d] bf16. Vt: [b,h,d,m] bf16.
__global__ __launch_bounds__(64) void attn(const bf16* __restrict__ Q, const bf16* __restrict__ Kb,
                                           const bf16* __restrict__ Vt, const int* __restrict__ ymask,
                                           bf16* __restrict__ att) {
    __shared__ bf16 Plds[16 * 40];   // padded stride 40
    int bid = blockIdx.x;
    int b = bid >> 9;
    int h = (bid >> 6) & 7;
    int n0 = (bid & 63) << 4;
    int lane = threadIdx.x, lr = lane & 15, q4 = lane >> 4;

    const bf16* qr = Q + (size_t)((b << 10) + n0 + lr) * 512 + h * 64 + q4 * 8;
    bf16x8 aq0 = *reinterpret_cast<const bf16x8*>(qr);
    bf16x8 aq1 = *reinterpret_cast<const bf16x8*>(qr + 32);
    const float scale = 0.044194173824159216f;   // 1/sqrt(512)

    f32x4 O[4] = {{0.f,0.f,0.f,0.f},{0.f,0.f,0.f,0.f},{0.f,0.f,0.f,0.f},{0.f,0.f,0.f,0.f}};
    float lsum[4] = {0.f, 0.f, 0.f, 0.f};
    const f32x4 z = {0.f, 0.f, 0.f, 0.f};

    for (int m0 = 0; m0 < M_; m0 += 32) {
        const bf16* kr0 = Kb + (size_t)((b << 10) + m0 + lr) * 512 + h * 64 + q4 * 8;
        const bf16* kr1 = kr0 + 16 * 512;
        f32x4 s0 = mfma16(aq0, *reinterpret_cast<const bf16x8*>(kr0), z);
        s0 = mfma16(aq1, *reinterpret_cast<const bf16x8*>(kr0 + 32), s0);
        f32x4 s1 = mfma16(aq0, *reinterpret_cast<const bf16x8*>(kr1), z);
        s1 = mfma16(aq1, *reinterpret_cast<const bf16x8*>(kr1 + 32), s1);

        int mk0 = ymask[(b << 10) + m0 + lr];
        int mk1 = ymask[(b << 10) + m0 + 16 + lr];
        float p0[4], p1[4];
#pragma unroll
        for (int r = 0; r < 4; ++r) {
            p0[r] = mk0 ? 0.0f : __expf(s0[r] * scale);
            p1[r] = mk1 ? 0.0f : __expf(s1[r] * scale);
            lsum[r] += p0[r] + p1[r];
        }
        __syncthreads();   // WAR: prior iteration's P reads done
#pragma unroll
        for (int r = 0; r < 4; ++r) {
            Plds[(q4 * 4 + r) * 40 + lr]      = (bf16)p0[r];
            Plds[(q4 * 4 + r) * 40 + 16 + lr] = (bf16)p1[r];
        }
        __syncthreads();   // RAW: P visible to all lanes
        bf16x8 ap = *reinterpret_cast<const bf16x8*>(&Plds[lr * 40 + q4 * 8]);
        const bf16* vr = Vt + (size_t)(((b * 8 + h) * 64) + lr) * 1024 + m0 + q4 * 8;
#pragma unroll
        for (int dt = 0; dt < 4; ++dt) {
            bf16x8 bv = *reinterpret_cast<const bf16x8*>(vr + (size_t)dt * 16 * 1024);
            O[dt] = mfma16(ap, bv, O[dt]);
        }
    }
#pragma unroll
    for (int r = 0; r < 4; ++r) {
        float v = lsum[r];
        v += __shfl_xor(v, 1); v += __shfl_xor(v, 2);
        v += __shfl_xor(v, 4); v += __shfl_xor(v, 8);
        lsum[r] = (v > 0.0f) ? v : 1.0f;
    }
#pragma unroll
    for (int dt = 0; dt < 4; ++dt)
#pragma unroll
        for (int r = 0; r < 4; ++r) {
            float v = O[dt][r] / lsum[r];
            att[(size_t)((b << 10) + n0 + q4 * 4 + r) * 512 + h * 64 + dt * 16 + lr] = (bf16)v;
        }
}

// ---------------- LayerNorms ----------------
__global__ __launch_bounds__(256) void ln1_k(const float* __restrict__ X, const float* __restrict__ R,
                                             const float* __restrict__ g, const float* __restrict__ be,
                                             float* __restrict__ O, bf16* __restrict__ Obf) {
    int row = blockIdx.x, t = threadIdx.x;
    size_t base = (size_t)row * 512;
    float t0 = X[base + t] + R[base + t];
    float t1 = X[base + 256 + t] + R[base + 256 + t];
    float s = t0 + t1, sq = t0 * t0 + t1 * t1;
#pragma unroll
    for (int off = 1; off < 64; off <<= 1) { s += __shfl_xor(s, off); sq += __shfl_xor(sq, off); }
    __shared__ float ls[4], lq[4];
    int w = t >> 6;
    if ((t & 63) == 0) { ls[w] = s; lq[w] = sq; }
    __syncthreads();
    s = ls[0] + ls[1] + ls[2] + ls[3];
    sq = lq[0] + lq[1] + lq[2] + lq[3];
    float mu = s * (1.0f / 512.0f);
    float var = sq * (1.0f / 512.0f) - mu * mu;
    float rs = rsqrtf(var + 1e-5f);
    float o0 = (t0 - mu) * rs * g[t] + be[t];
    float o1 = (t1 - mu) * rs * g[256 + t] + be[256 + t];
    O[base + t] = o0; O[base + 256 + t] = o1;
    Obf[base + t] = (bf16)o0; Obf[base + 256 + t] = (bf16)o1;
}

__global__ __launch_bounds__(256) void ln2_k(const float* __restrict__ O, const float* __restrict__ F,
                                             const float* __restrict__ g, const float* __restrict__ be,
                                             const int* __restrict__ xmask, float* __restrict__ out) {
    int row = blockIdx.x, t = threadIdx.x;
    size_t base = (size_t)row * 512;
    float t0 = O[base + t] + F[base + t];
    float t1 = O[base + 256 + t] + F[base + 256 + t];
    float s = t0 + t1, sq = t0 * t0 + t1 * t1;
#pragma unroll
    for (int off = 1; off < 64; off <<= 1) { s += __shfl_xor(s, off); sq += __shfl_xor(sq, off); }
    __shared__ float ls[4], lq[4];
    int w = t >> 6;
    if ((t & 63) == 0) { ls[w] = s; lq[w] = sq; }
    __syncthreads();
    s = ls[0] + ls[1] + ls[2] + ls[3];
    sq = lq[0] + lq[1] + lq[2] + lq[3];
    float mu = s * (1.0f / 512.0f);
    float var = sq * (1.0f / 512.0f) - mu * mu;
    float rs = rsqrtf(var + 1e-5f);
    int msk = xmask[row];
    float o0 = (t0 - mu) * rs * g[t] + be[t];
    float o1 = (t1 - mu) * rs * g[256 + t] + be[256 + t];
    out[base + t] = msk ? 0.0f : o0;
    out[base + 256 + t] = msk ? 0.0f : o1;
}

// ---------------- launcher ----------------
extern "C" void kernel_launch(void* const* d_in, const int* in_sizes, int n_in,
                              void* d_out, int out_size, void* d_ws, size_t ws_size,
                              hipStream_t stream) {
    const float* x   = (const float*)d_in[0];
    const float* y   = (const float*)d_in[1];
    const int*   xm  = (const int*)d_in[2];
    const int*   ym  = (const int*)d_in[3];
    const float* Wq  = (const float*)d_in[4];
    const float* Wk  = (const float*)d_in[5];
    const float* Wv  = (const float*)d_in[6];
    const float* Wo  = (const float*)d_in[7];
    const float* W1  = (const float*)d_in[8];
    const float* b1  = (const float*)d_in[9];
    const float* W2  = (const float*)d_in[10];
    const float* b2  = (const float*)d_in[11];
    const float* g1  = (const float*)d_in[12];
    const float* be1 = (const float*)d_in[13];
    const float* g2  = (const float*)d_in[14];
    const float* be2 = (const float*)d_in[15];

    char* ws = (char*)d_ws;
    const size_t WT_SZ  = 512 * 512 * sizeof(bf16);      // 512 KB
    const size_t XB_SZ  = (size_t)ROWS_ * 512 * sizeof(bf16);   // 8 MB
    const size_t F32_SZ = (size_t)ROWS_ * 512 * sizeof(float);  // 16 MB

    bf16* Wqt = (bf16*)(ws + 0 * WT_SZ);
    bf16* Wkt = (bf16*)(ws + 1 * WT_SZ);
    bf16* Wvt = (bf16*)(ws + 2 * WT_SZ);
    bf16* Wot = (bf16*)(ws + 3 * WT_SZ);
    bf16* W1t = (bf16*)(ws + 4 * WT_SZ);
    bf16* W2t = (bf16*)(ws + 5 * WT_SZ);
    size_t off = 6 * WT_SZ;
    bf16* Xb  = (bf16*)(ws + off); off += XB_SZ;
    bf16* Yb  = (bf16*)(ws + off); off += XB_SZ;
    bf16* qb  = (bf16*)(ws + off); off += XB_SZ;
    bf16* kb  = (bf16*)(ws + off); off += XB_SZ;
    bf16* vb  = (bf16*)(ws + off); off += XB_SZ;
    bf16* Vt  = (bf16*)(ws + off); off += XB_SZ;
    float* awo = (float*)(ws + off); off += F32_SZ;
    float* ob  = (float*)(ws + off); off += F32_SZ;
    // reuse dead buffers:
    bf16* attb = Xb;   // Xb dead after q projection
    bf16* obf  = qb;   // qb dead after attention
    bf16* hb   = Yb;   // Yb dead after v projection
    float* fb  = awo;  // awo dead after ln1

    const int NELT = ROWS_ * 512;   // 4194304
    cvt_bf16<<<NELT / 256, 256, 0, stream>>>(x, Xb, NELT);
    cvt_bf16<<<NELT / 256, 256, 0, stream>>>(y, Yb, NELT);
    wtrans<<<1024, 256, 0, stream>>>(Wq, Wqt);
    wtrans<<<1024, 256, 0, stream>>>(Wk, Wkt);
    wtrans<<<1024, 256, 0, stream>>>(Wv, Wvt);
    wtrans<<<1024, 256, 0, stream>>>(Wo, Wot);
    wtrans<<<1024, 256, 0, stream>>>(W1, W1t);
    wtrans<<<1024, 256, 0, stream>>>(W2, W2t);

    dim3 gg(ROWS_ / 64, 512 / 64, 1);
    gemm_bt<1><<<gg, 256, 0, stream>>>(Xb, Wqt, nullptr, qb);
    gemm_bt<1><<<gg, 256, 0, stream>>>(Yb, Wkt, nullptr, kb);
    gemm_bt<1><<<gg, 256, 0, stream>>>(Yb, Wvt, nullptr, vb);
    vtrans<<<NELT / 256, 256, 0, stream>>>(vb, Vt);

    attn<<<B_ * H_ * (N_ / 16), 64, 0, stream>>>(qb, kb, Vt, ym, attb);

    gemm_bt<0><<<gg, 256, 0, stream>>>(attb, Wot, nullptr, awo);
    ln1_k<<<ROWS_, 256, 0, stream>>>(x, awo, g1, be1, ob, obf);
    gemm_bt<3><<<gg, 256, 0, stream>>>(obf, W1t, b1, hb);
    gemm_bt<2><<<gg, 256, 0, stream>>>(hb, W2t, b2, fb);
    ln2_k<<<ROWS_, 256, 0, stream>>>(ob, fb, g2, be2, xm, (float*)d_out);
}

// Round 2
// 239.448 us; speedup vs baseline: 2.1625x; 2.1625x over previous
//
#include <hip/hip_runtime.h>
#include <hip/hip_bf16.h>

typedef __bf16 bf16;
typedef __attribute__((ext_vector_type(4))) __bf16 bf16x4;
typedef __attribute__((ext_vector_type(8))) __bf16 bf16x8;
typedef __attribute__((ext_vector_type(4))) float f32x4;

#define B_ 8
#define N_ 1024
#define M_ 1024
#define H_ 8
#define ROWS_ (B_ * N_)   // 8192

__device__ __forceinline__ f32x4 mfma16(bf16x8 a, bf16x8 b, f32x4 c) {
    return __builtin_amdgcn_mfma_f32_16x16x32_bf16(a, b, c, 0, 0, 0);
}

// async global->LDS, 16B per lane. lds dst is wave-uniform base + lane*16.
__device__ __forceinline__ void glds16(const void* g, void* l) {
    __builtin_amdgcn_global_load_lds((const __attribute__((address_space(1))) void*)g,
                                     (__attribute__((address_space(3))) void*)l, 16, 0, 0);
}

// ---------------- conversions ----------------
__global__ void cvt_bf16(const float* __restrict__ in, bf16* __restrict__ out) {
    int i = blockIdx.x * 256 + threadIdx.x;
    float4 f = ((const float4*)in)[i];
    bf16x4 o = {(bf16)f.x, (bf16)f.y, (bf16)f.z, (bf16)f.w};
    ((bf16x4*)out)[i] = o;
}

// 6 weight transposes in one launch. Wt[n*512+k] = W[k*512+n]
__global__ void wtrans6(const float* W0, const float* W1, const float* W2,
                        const float* W3, const float* W4, const float* W5,
                        bf16* T0, bf16* T1, bf16* T2, bf16* T3, bf16* T4, bf16* T5) {
    const float* srcs[6] = {W0, W1, W2, W3, W4, W5};
    bf16* dsts[6] = {T0, T1, T2, T3, T4, T5};
    int j = blockIdx.y;
    const float* W = srcs[j];
    bf16* Wt = dsts[j];
    int i = blockIdx.x * 256 + threadIdx.x;   // i = n*512 + k
    int n = i >> 9, k = i & 511;
    Wt[i] = (bf16)W[k * 512 + n];
}

// ---------------- GEMM: C[rows x 512] = A[rows,512] x Bt[col][k] ----------------
// tile 128(rows of A) x 64(rows of Bt), BK=64, 4 waves, LDS-staged via glds.
// MODE: 0 fp32 out; 1 bf16 out; 2 fp32+bias; 3 bf16+bias+relu;
//       4 bf16 out scattered to Vt layout (A=Wvt rows=out-cols, Bt=Y rows=out-rows)
template <int MODE>
__global__ __launch_bounds__(256) void gemm_bt(const bf16* __restrict__ A,
                                               const bf16* __restrict__ Bt,
                                               const float* __restrict__ bias,
                                               void* __restrict__ Cout) {
    __shared__ bf16 As[128 * 64];   // 16 KB, 8x16B blocks/row, blk^=(row&7)
    __shared__ bf16 Bs[64 * 64];    // 8 KB
    const int K = 512;
    int tid = threadIdx.x;
    int wave = tid >> 6, lane = tid & 63;
    int lr = lane & 15, q4 = lane >> 4;
    int row0 = blockIdx.x * 128;
    int col0 = blockIdx.y * 64;

    // staging: A-tile 1024 chunks (4/thread), B-tile 512 chunks (2/thread)
    const bf16* Asrc[4];
    const bf16* Bsrc[2];
#pragma unroll
    for (int s = 0; s < 4; ++s) {
        int c = tid + s * 256;
        int r = c >> 3, bk = (c & 7) ^ (r & 7);
        Asrc[s] = A + (size_t)(row0 + r) * K + bk * 8;
    }
#pragma unroll
    for (int s = 0; s < 2; ++s) {
        int c = tid + s * 256;
        int r = c >> 3, bk = (c & 7) ^ (r & 7);
        Bsrc[s] = Bt + (size_t)(col0 + r) * K + bk * 8;
    }
    int wb = wave * 1024;   // bytes: 64 chunks per wave

    const f32x4 z = {0.f, 0.f, 0.f, 0.f};
    f32x4 acc[2][4];
#pragma unroll
    for (int rt = 0; rt < 2; ++rt)
#pragma unroll
        for (int ct = 0; ct < 4; ++ct) acc[rt][ct] = z;

    for (int k0 = 0; k0 < K; k0 += 64) {
        __syncthreads();
#pragma unroll
        for (int s = 0; s < 4; ++s) glds16(Asrc[s] + k0, (char*)As + s * 4096 + wb);
#pragma unroll
        for (int s = 0; s < 2; ++s) glds16(Bsrc[s] + k0, (char*)Bs + s * 4096 + wb);
        __syncthreads();

        bf16x8 af[2][2], bfr[4][2];
#pragma unroll
        for (int rt = 0; rt < 2; ++rt) {
            int row = wave * 32 + rt * 16 + lr;
#pragma unroll
            for (int c = 0; c < 2; ++c) {
                int idx = row * 8 + ((c * 4 + q4) ^ (row & 7));
                af[rt][c] = *(const bf16x8*)((const char*)As + idx * 16);
            }
        }
#pragma unroll
        for (int ct = 0; ct < 4; ++ct) {
            int col = ct * 16 + lr;
#pragma unroll
            for (int c = 0; c < 2; ++c) {
                int idx = col * 8 + ((c * 4 + q4) ^ (col & 7));
                bfr[ct][c] = *(const bf16x8*)((const char*)Bs + idx * 16);
            }
        }
#pragma unroll
        for (int rt = 0; rt < 2; ++rt)
#pragma unroll
            for (int ct = 0; ct < 4; ++ct) {
                acc[rt][ct] = mfma16(af[rt][0], bfr[ct][0], acc[rt][ct]);
                acc[rt][ct] = mfma16(af[rt][1], bfr[ct][1], acc[rt][ct]);
            }
    }

#pragma unroll
    for (int rt = 0; rt < 2; ++rt)
#pragma unroll
        for (int ct = 0; ct < 4; ++ct) {
            int col = col0 + ct * 16 + lr;
            float bv = (MODE == 2 || MODE == 3) ? bias[col] : 0.0f;
#pragma unroll
            for (int r = 0; r < 4; ++r) {
                int row = row0 + wave * 32 + rt * 16 + q4 * 4 + r;
                float v = acc[rt][ct][r] + bv;
                if (MODE == 3) v = fmaxf(v, 0.0f);
                if (MODE == 0 || MODE == 2)
                    ((float*)Cout)[(size_t)row * 512 + col] = v;
                else if (MODE == 4)
                    ((bf16*)Cout)[(size_t)((col >> 10) * 512 + row) * 1024 + (col & 1023)] = (bf16)v;
                else
                    ((bf16*)Cout)[(size_t)row * 512 + col] = (bf16)v;
            }
        }
}

// ---------------- attention ----------------
// block: 256 thr (4 waves), Q-tile 128 (wave owns 32 q rows), key loop in 64-chunks.
// Q,K: [b, n, h*64+d] bf16.  Vt: [b*512 + h*64 + d, m] bf16.
__global__ __launch_bounds__(256) void attn(const bf16* __restrict__ Q, const bf16* __restrict__ Kb,
                                            const bf16* __restrict__ Vt, const int* __restrict__ ymask,
                                            bf16* __restrict__ att) {
    __shared__ bf16 Ks[64 * 64];        // [key][d], swizzled blk^=(key&7)
    __shared__ bf16 Vs[64 * 64];        // [d][m],  swizzled blk^=(d&7)
    __shared__ bf16 Ps[4][32 * 72];     // per-wave P [q][key], stride 72 (pad 8)

    int bid = blockIdx.x;
    int b = bid >> 6, h = (bid >> 3) & 7, n0 = (bid & 7) * 128;
    int tid = threadIdx.x, wave = tid >> 6, lane = tid & 63;
    int lr = lane & 15, q4 = lane >> 4;
    const float scale = 0.044194173824159216f;   // 1/sqrt(512)

    // Q fragments (held in registers for whole kernel)
    bf16x8 aq[2][2];
#pragma unroll
    for (int rt = 0; rt < 2; ++rt) {
        const bf16* qp = Q + (size_t)((b << 10) + n0 + wave * 32 + rt * 16 + lr) * 512 + h * 64 + q4 * 8;
        aq[rt][0] = *(const bf16x8*)qp;
        aq[rt][1] = *(const bf16x8*)(qp + 32);
    }

    // staging addresses (2 chunks/thread for each of K,V)
    const bf16* Ksrc[2];
    const bf16* Vsrc[2];
    int crow[2];
#pragma unroll
    for (int s = 0; s < 2; ++s) {
        int c = tid + s * 256;
        int r = c >> 3, bk = (c & 7) ^ (r & 7);
        crow[s] = r;
        Ksrc[s] = Kb + (size_t)((b << 10) + r) * 512 + h * 64 + bk * 8;
        Vsrc[s] = Vt + (size_t)(b * 512 + h * 64 + r) * 1024 + bk * 8;
    }
    int wb = wave * 1024;

    const f32x4 z = {0.f, 0.f, 0.f, 0.f};
    f32x4 O[2][4];
    float lsum[2][4];
#pragma unroll
    for (int rt = 0; rt < 2; ++rt) {
#pragma unroll
        for (int dt = 0; dt < 4; ++dt) O[rt][dt] = z;
#pragma unroll
        for (int r = 0; r < 4; ++r) lsum[rt][r] = 0.f;
    }

    for (int m0 = 0; m0 < M_; m0 += 64) {
        __syncthreads();
#pragma unroll
        for (int s = 0; s < 2; ++s) {
            glds16(Ksrc[s] + (size_t)m0 * 512, (char*)Ks + s * 4096 + wb);
            glds16(Vsrc[s] + m0, (char*)Vs + s * 4096 + wb);
        }
        __syncthreads();

        // QK^T -> masked exp -> P into per-wave LDS
#pragma unroll
        for (int nt = 0; nt < 4; ++nt) {
            int krow = nt * 16 + lr;
            bf16x8 kf0 = *(const bf16x8*)((const char*)Ks + (krow * 8 + ((q4) ^ (krow & 7))) * 16);
            bf16x8 kf1 = *(const bf16x8*)((const char*)Ks + (krow * 8 + ((4 + q4) ^ (krow & 7))) * 16);
            int mk = ymask[(b << 10) + m0 + krow];
#pragma unroll
            for (int rt = 0; rt < 2; ++rt) {
                f32x4 s = mfma16(aq[rt][0], kf0, z);
                s = mfma16(aq[rt][1], kf1, s);
#pragma unroll
                for (int r = 0; r < 4; ++r) {
                    float p = mk ? 0.0f : __expf(s[r] * scale);
                    lsum[rt][r] += p;
                    Ps[wave][(rt * 16 + q4 * 4 + r) * 72 + krow] = (bf16)p;
                }
            }
        }
        __syncthreads();

        // P x V
        bf16x8 ap[2][2];
#pragma unroll
        for (int rt = 0; rt < 2; ++rt)
#pragma unroll
            for (int c = 0; c < 2; ++c)
                ap[rt][c] = *(const bf16x8*)&Ps[wave][(rt * 16 + lr) * 72 + c * 32 + q4 * 8];
#pragma unroll
        for (int dt = 0; dt < 4; ++dt) {
            int vrow = dt * 16 + lr;
            bf16x8 vf0 = *(const bf16x8*)((const char*)Vs + (vrow * 8 + ((q4) ^ (vrow & 7))) * 16);
            bf16x8 vf1 = *(const bf16x8*)((const char*)Vs + (vrow * 8 + ((4 + q4) ^ (vrow & 7))) * 16);
#pragma unroll
            for (int rt = 0; rt < 2; ++rt) {
                O[rt][dt] = mfma16(ap[rt][0], vf0, O[rt][dt]);
                O[rt][dt] = mfma16(ap[rt][1], vf1, O[rt][dt]);
            }
        }
    }

    // normalize + store
#pragma unroll
    for (int rt = 0; rt < 2; ++rt)
#pragma unroll
        for (int r = 0; r < 4; ++r) {
            float v = lsum[rt][r];
            v += __shfl_xor(v, 1); v += __shfl_xor(v, 2);
            v += __shfl_xor(v, 4); v += __shfl_xor(v, 8);
            lsum[rt][r] = (v > 0.0f) ? (1.0f / v) : 0.0f;
        }
#pragma unroll
    for (int rt = 0; rt < 2; ++rt)
#pragma unroll
        for (int dt = 0; dt < 4; ++dt)
#pragma unroll
            for (int r = 0; r < 4; ++r) {
                int row = n0 + wave * 32 + rt * 16 + q4 * 4 + r;
                att[(size_t)((b << 10) + row) * 512 + h * 64 + dt * 16 + lr] =
                    (bf16)(O[rt][dt][r] * lsum[rt][r]);
            }
}

// ---------------- LayerNorms ----------------
__global__ __launch_bounds__(256) void ln1_k(const float* __restrict__ X, const float* __restrict__ R,
                                             const float* __restrict__ g, const float* __restrict__ be,
                                             float* __restrict__ O, bf16* __restrict__ Obf) {
    int row = blockIdx.x, t = threadIdx.x;
    size_t base = (size_t)row * 512;
    float t0 = X[base + t] + R[base + t];
    float t1 = X[base + 256 + t] + R[base + 256 + t];
    float s = t0 + t1, sq = t0 * t0 + t1 * t1;
#pragma unroll
    for (int off = 1; off < 64; off <<= 1) { s += __shfl_xor(s, off); sq += __shfl_xor(sq, off); }
    __shared__ float ls[4], lq[4];
    int w = t >> 6;
    if ((t & 63) == 0) { ls[w] = s; lq[w] = sq; }
    __syncthreads();
    s = ls[0] + ls[1] + ls[2] + ls[3];
    sq = lq[0] + lq[1] + lq[2] + lq[3];
    float mu = s * (1.0f / 512.0f);
    float var = sq * (1.0f / 512.0f) - mu * mu;
    float rs = rsqrtf(var + 1e-5f);
    float o0 = (t0 - mu) * rs * g[t] + be[t];
    float o1 = (t1 - mu) * rs * g[256 + t] + be[256 + t];
    O[base + t] = o0; O[base + 256 + t] = o1;
    Obf[base + t] = (bf16)o0; Obf[base + 256 + t] = (bf16)o1;
}

__global__ __launch_bounds__(256) void ln2_k(const float* __restrict__ O, const float* __restrict__ F,
                                             const float* __restrict__ g, const float* __restrict__ be,
                                             const int* __restrict__ xmask, float* __restrict__ out) {
    int row = blockIdx.x, t = threadIdx.x;
    size_t base = (size_t)row * 512;
    float t0 = O[base + t] + F[base + t];
    float t1 = O[base + 256 + t] + F[base + 256 + t];
    float s = t0 + t1, sq = t0 * t0 + t1 * t1;
#pragma unroll
    for (int off = 1; off < 64; off <<= 1) { s += __shfl_xor(s, off); sq += __shfl_xor(sq, off); }
    __shared__ float ls[4], lq[4];
    int w = t >> 6;
    if ((t & 63) == 0) { ls[w] = s; lq[w] = sq; }
    __syncthreads();
    s = ls[0] + ls[1] + ls[2] + ls[3];
    sq = lq[0] + lq[1] + lq[2] + lq[3];
    float mu = s * (1.0f / 512.0f);
    float var = sq * (1.0f / 512.0f) - mu * mu;
    float rs = rsqrtf(var + 1e-5f);
    int msk = xmask[row];
    float o0 = (t0 - mu) * rs * g[t] + be[t];
    float o1 = (t1 - mu) * rs * g[256 + t] + be[256 + t];
    out[base + t] = msk ? 0.0f : o0;
    out[base + 256 + t] = msk ? 0.0f : o1;
}

// ---------------- launcher ----------------
extern "C" void kernel_launch(void* const* d_in, const int* in_sizes, int n_in,
                              void* d_out, int out_size, void* d_ws, size_t ws_size,
                              hipStream_t stream) {
    const float* x   = (const float*)d_in[0];
    const float* y   = (const float*)d_in[1];
    const int*   xm  = (const int*)d_in[2];
    const int*   ym  = (const int*)d_in[3];
    const float* Wq  = (const float*)d_in[4];
    const float* Wk  = (const float*)d_in[5];
    const float* Wv  = (const float*)d_in[6];
    const float* Wo  = (const float*)d_in[7];
    const float* W1  = (const float*)d_in[8];
    const float* b1  = (const float*)d_in[9];
    const float* W2  = (const float*)d_in[10];
    const float* b2  = (const float*)d_in[11];
    const float* g1  = (const float*)d_in[12];
    const float* be1 = (const float*)d_in[13];
    const float* g2  = (const float*)d_in[14];
    const float* be2 = (const float*)d_in[15];

    char* ws = (char*)d_ws;
    const size_t WT_SZ  = 512 * 512 * sizeof(bf16);             // 512 KB
    const size_t XB_SZ  = (size_t)ROWS_ * 512 * sizeof(bf16);   // 8 MB
    const size_t F32_SZ = (size_t)ROWS_ * 512 * sizeof(float);  // 16 MB

    bf16* Wqt = (bf16*)(ws + 0 * WT_SZ);
    bf16* Wkt = (bf16*)(ws + 1 * WT_SZ);
    bf16* Wvt = (bf16*)(ws + 2 * WT_SZ);
    bf16* Wot = (bf16*)(ws + 3 * WT_SZ);
    bf16* W1t = (bf16*)(ws + 4 * WT_SZ);
    bf16* W2t = (bf16*)(ws + 5 * WT_SZ);
    size_t off = 6 * WT_SZ;
    bf16* Xb  = (bf16*)(ws + off); off += XB_SZ;
    bf16* Yb  = (bf16*)(ws + off); off += XB_SZ;
    bf16* qb  = (bf16*)(ws + off); off += XB_SZ;
    bf16* kb  = (bf16*)(ws + off); off += XB_SZ;
    bf16* Vt  = (bf16*)(ws + off); off += XB_SZ;
    float* awo = (float*)(ws + off); off += F32_SZ;
    float* ob  = (float*)(ws + off); off += F32_SZ;
    // reuse dead buffers:
    bf16* attb = Xb;   // Xb dead after q projection
    bf16* obf  = qb;   // qb dead after attention
    bf16* hb   = Yb;   // Yb dead after v projection
    float* fb  = awo;  // awo dead after ln1

    const int NELT = ROWS_ * 512;   // 4194304
    cvt_bf16<<<NELT / 1024, 256, 0, stream>>>(x, Xb);
    cvt_bf16<<<NELT / 1024, 256, 0, stream>>>(y, Yb);
    wtrans6<<<dim3(1024, 6), 256, 0, stream>>>(Wq, Wk, Wv, Wo, W1, W2,
                                               Wqt, Wkt, Wvt, Wot, W1t, W2t);

    dim3 gg(ROWS_ / 128, 512 / 64);
    gemm_bt<1><<<gg, 256, 0, stream>>>(Xb, Wqt, nullptr, qb);
    gemm_bt<1><<<gg, 256, 0, stream>>>(Yb, Wkt, nullptr, kb);
    gemm_bt<4><<<dim3(512 / 128, ROWS_ / 64), 256, 0, stream>>>(Wvt, Yb, nullptr, Vt);

    attn<<<B_ * H_ * (N_ / 128), 256, 0, stream>>>(qb, kb, Vt, ym, attb);

    gemm_bt<0><<<gg, 256, 0, stream>>>(attb, Wot, nullptr, awo);
    ln1_k<<<ROWS_, 256, 0, stream>>>(x, awo, g1, be1, ob, obf);
    gemm_bt<3><<<gg, 256, 0, stream>>>(obf, W1t, b1, hb);
    gemm_bt<2><<<gg, 256, 0, stream>>>(hb, W2t, b2, fb);
    ln2_k<<<ROWS_, 256, 0, stream>>>(ob, fb, g2, be2, xm, (float*)d_out);
}

// Round 3
// 224.868 us; speedup vs baseline: 2.3027x; 1.0648x over previous
//
#include <hip/hip_runtime.h>
#include <hip/hip_bf16.h>

typedef __bf16 bf16;
typedef __attribute__((ext_vector_type(4))) __bf16 bf16x4;
typedef __attribute__((ext_vector_type(8))) __bf16 bf16x8;
typedef __attribute__((ext_vector_type(4))) float f32x4;

#define B_ 8
#define N_ 1024
#define M_ 1024
#define H_ 8
#define ROWS_ (B_ * N_)   // 8192

__device__ __forceinline__ f32x4 mfma16(bf16x8 a, bf16x8 b, f32x4 c) {
    return __builtin_amdgcn_mfma_f32_16x16x32_bf16(a, b, c, 0, 0, 0);
}

__device__ __forceinline__ void glds16(const void* g, void* l) {
    __builtin_amdgcn_global_load_lds((const __attribute__((address_space(1))) void*)g,
                                     (__attribute__((address_space(3))) void*)l, 16, 0, 0);
}

// ---------------- conversions ----------------
// x (4M floats) and y (4M floats) -> bf16 in one launch
__global__ void cvt2(const float4* __restrict__ x, const float4* __restrict__ y,
                     bf16x4* __restrict__ Xb, bf16x4* __restrict__ Yb) {
    int i = blockIdx.x * 256 + threadIdx.x;   // 0 .. 2M-1 (float4 groups)
    const float4* s;
    bf16x4* d;
    int j;
    if (i < 1048576) { s = x; d = Xb; j = i; }
    else             { s = y; d = Yb; j = i - 1048576; }
    float4 f = s[j];
    bf16x4 o = {(bf16)f.x, (bf16)f.y, (bf16)f.z, (bf16)f.w};
    d[j] = o;
}

// 6 weight transposes, LDS-tiled (coalesced read AND write). Wt[n*512+k] = W[k*512+n]
__global__ __launch_bounds__(256) void wtrans6(const float* W0, const float* W1, const float* W2,
                                               const float* W3, const float* W4, const float* W5,
                                               bf16* T0, bf16* T1, bf16* T2, bf16* T3, bf16* T4, bf16* T5) {
    __shared__ float t[64][65];
    const float* srcs[6] = {W0, W1, W2, W3, W4, W5};
    bf16* dsts[6] = {T0, T1, T2, T3, T4, T5};
    const float* W = srcs[blockIdx.y];
    bf16* Wt = dsts[blockIdx.y];
    int k0 = (blockIdx.x >> 3) * 64, n0 = (blockIdx.x & 7) * 64;
    int tx = threadIdx.x & 63, ty = threadIdx.x >> 6;
#pragma unroll
    for (int j = 0; j < 16; ++j)
        t[ty + j * 4][tx] = W[(size_t)(k0 + ty + j * 4) * 512 + n0 + tx];
    __syncthreads();
#pragma unroll
    for (int j = 0; j < 16; ++j)
        Wt[(size_t)(n0 + ty + j * 4) * 512 + k0 + tx] = (bf16)t[tx][ty + j * 4];
}

// ---------------- GEMM core: 128(A-rows) x 64(Bt-rows) tile, BK=64, 8 waves ----------------
// As/Bs swizzled: 16B block index ^= (row&7). Wave w computes rows w*16..w*16+15.
__device__ __forceinline__ void gemm_core(const bf16* __restrict__ A, const bf16* __restrict__ Bt,
                                          int row0, int col0, bf16* As, bf16* Bs, f32x4* acc) {
    int tid = threadIdx.x, wave = tid >> 6, lane = tid & 63;
    int lr = lane & 15, q4 = lane >> 4;
    int r0 = tid >> 3, bk0 = (tid & 7) ^ (r0 & 7);
    int c1 = tid + 512, r1 = c1 >> 3, bk1 = (c1 & 7) ^ (r1 & 7);
    const bf16* Asrc0 = A + (size_t)(row0 + r0) * 512 + bk0 * 8;
    const bf16* Asrc1 = A + (size_t)(row0 + r1) * 512 + bk1 * 8;
    const bf16* Bsrc  = Bt + (size_t)(col0 + r0) * 512 + bk0 * 8;
    int wb = wave * 1024;
    for (int k0 = 0; k0 < 512; k0 += 64) {
        __syncthreads();
        glds16(Asrc0 + k0, (char*)As + wb);
        glds16(Asrc1 + k0, (char*)As + 8192 + wb);
        glds16(Bsrc + k0, (char*)Bs + wb);
        __syncthreads();
        int row = wave * 16 + lr;
        bf16x8 af0 = *(const bf16x8*)((const char*)As + (row * 8 + (q4 ^ (row & 7))) * 16);
        bf16x8 af1 = *(const bf16x8*)((const char*)As + (row * 8 + ((4 + q4) ^ (row & 7))) * 16);
#pragma unroll
        for (int ct = 0; ct < 4; ++ct) {
            int col = ct * 16 + lr;
            bf16x8 bf0 = *(const bf16x8*)((const char*)Bs + (col * 8 + (q4 ^ (col & 7))) * 16);
            bf16x8 bf1 = *(const bf16x8*)((const char*)Bs + (col * 8 + ((4 + q4) ^ (col & 7))) * 16);
            acc[ct] = mfma16(af0, bf0, acc[ct]);
            acc[ct] = mfma16(af1, bf1, acc[ct]);
        }
    }
}

// fused QKV projections. z=0: q = Xb@Wq; z=1: k = Yb@Wk; z=2: Vt = (Yb@Wv)^T scattered
__global__ __launch_bounds__(512) void proj_qkv(const bf16* __restrict__ Xb, const bf16* __restrict__ Yb,
                                                const bf16* __restrict__ Wqt, const bf16* __restrict__ Wkt,
                                                const bf16* __restrict__ Wvt,
                                                bf16* __restrict__ qb, bf16* __restrict__ kb,
                                                bf16* __restrict__ Vt) {
    __shared__ bf16 As[128 * 64];
    __shared__ bf16 Bs[64 * 64];
    int z = blockIdx.z;
    const bf16 *A, *Bt;
    int row0, col0;
    if (z == 0)      { A = Xb;  Bt = Wqt; row0 = blockIdx.x * 128; col0 = blockIdx.y * 64; }
    else if (z == 1) { A = Yb;  Bt = Wkt; row0 = blockIdx.x * 128; col0 = blockIdx.y * 64; }
    else { A = Wvt; Bt = Yb; int flat = blockIdx.y * 64 + blockIdx.x; row0 = (flat & 3) * 128; col0 = (flat >> 2) * 64; }
    const f32x4 z4 = {0.f, 0.f, 0.f, 0.f};
    f32x4 acc[4] = {z4, z4, z4, z4};
    gemm_core(A, Bt, row0, col0, As, Bs, acc);
    int wave = threadIdx.x >> 6, lane = threadIdx.x & 63, lr = lane & 15, q4 = lane >> 4;
    bf16* dst = (z == 0) ? qb : kb;
#pragma unroll
    for (int ct = 0; ct < 4; ++ct) {
        int col = col0 + ct * 16 + lr;
#pragma unroll
        for (int r = 0; r < 4; ++r) {
            int row = row0 + wave * 16 + q4 * 4 + r;
            bf16 v = (bf16)acc[ct][r];
            if (z < 2) dst[(size_t)row * 512 + col] = v;
            else Vt[(size_t)((col >> 10) * 512 + row) * 1024 + (col & 1023)] = v;
        }
    }
}

// MODE: 0 fp32 out; 2 fp32+bias; 3 bf16+bias+relu
template <int MODE>
__global__ __launch_bounds__(512) void gemm_bt(const bf16* __restrict__ A, const bf16* __restrict__ Bt,
                                               const float* __restrict__ bias, void* __restrict__ Cout) {
    __shared__ bf16 As[128 * 64];
    __shared__ bf16 Bs[64 * 64];
    int row0 = blockIdx.x * 128, col0 = blockIdx.y * 64;
    const f32x4 z4 = {0.f, 0.f, 0.f, 0.f};
    f32x4 acc[4] = {z4, z4, z4, z4};
    gemm_core(A, Bt, row0, col0, As, Bs, acc);
    int wave = threadIdx.x >> 6, lane = threadIdx.x & 63, lr = lane & 15, q4 = lane >> 4;
#pragma unroll
    for (int ct = 0; ct < 4; ++ct) {
        int col = col0 + ct * 16 + lr;
        float bv = (MODE >= 2) ? bias[col] : 0.0f;
#pragma unroll
        for (int r = 0; r < 4; ++r) {
            int row = row0 + wave * 16 + q4 * 4 + r;
            float v = acc[ct][r] + bv;
            if (MODE == 3) v = fmaxf(v, 0.0f);
            if (MODE == 3) ((bf16*)Cout)[(size_t)row * 512 + col] = (bf16)v;
            else           ((float*)Cout)[(size_t)row * 512 + col] = v;
        }
    }
}

// ---------------- attention ----------------
// 512 thr (8 waves), Q-tile 128 (wave owns 16 q rows), 64-key chunks staged to LDS.
// bid swizzle: bid = n0tile*64 + (b*8+h) so same-(b,h) blocks share an XCD.
__global__ __launch_bounds__(512) void attn(const bf16* __restrict__ Q, const bf16* __restrict__ Kb,
                                            const bf16* __restrict__ Vt, const int* __restrict__ ymask,
                                            bf16* __restrict__ att) {
    __shared__ bf16 Ks[64 * 64];        // [key][d], swizzled
    __shared__ bf16 Vs[64 * 64];        // [d][m], swizzled
    __shared__ bf16 Ps[8][16 * 72];     // per-wave P [q][key], stride 72

    int bid = blockIdx.x;
    int bh = bid & 63, n0 = (bid >> 6) * 128;
    int b = bh >> 3, h = bh & 7;
    int tid = threadIdx.x, wave = tid >> 6, lane = tid & 63;
    int lr = lane & 15, q4 = lane >> 4;
    const float scale = 0.044194173824159216f;   // 1/sqrt(512)

    const bf16* qp = Q + (size_t)((b << 10) + n0 + wave * 16 + lr) * 512 + h * 64 + q4 * 8;
    bf16x8 aq0 = *(const bf16x8*)qp;
    bf16x8 aq1 = *(const bf16x8*)(qp + 32);

    int r = tid >> 3, bk = (tid & 7) ^ (r & 7);
    const bf16* Ksrc = Kb + (size_t)((b << 10) + r) * 512 + h * 64 + bk * 8;
    const bf16* Vsrc = Vt + (size_t)(b * 512 + h * 64 + r) * 1024 + bk * 8;
    int wb = wave * 1024;

    const f32x4 zv = {0.f, 0.f, 0.f, 0.f};
    f32x4 O[4] = {zv, zv, zv, zv};
    float lsum[4] = {0.f, 0.f, 0.f, 0.f};

    for (int m0 = 0; m0 < M_; m0 += 64) {
        int mk = ymask[(b << 10) + m0 + lane];
        __syncthreads();
        glds16(Ksrc + (size_t)m0 * 512, (char*)Ks + wb);
        glds16(Vsrc + m0, (char*)Vs + wb);
        __syncthreads();

#pragma unroll
        for (int nt = 0; nt < 4; ++nt) {
            int krow = nt * 16 + lr;
            bf16x8 kf0 = *(const bf16x8*)((const char*)Ks + (krow * 8 + (q4 ^ (krow & 7))) * 16);
            bf16x8 kf1 = *(const bf16x8*)((const char*)Ks + (krow * 8 + ((4 + q4) ^ (krow & 7))) * 16);
            int mkv = __shfl(mk, krow);
            f32x4 s = mfma16(aq0, kf0, zv);
            s = mfma16(aq1, kf1, s);
#pragma unroll
            for (int rr = 0; rr < 4; ++rr) {
                float p = mkv ? 0.0f : __expf(s[rr] * scale);
                lsum[rr] += p;
                Ps[wave][(q4 * 4 + rr) * 72 + krow] = (bf16)p;
            }
        }
        // Ps is per-wave: in-wave lgkmcnt ordering suffices, no barrier
        bf16x8 ap0 = *(const bf16x8*)&Ps[wave][lr * 72 + q4 * 8];
        bf16x8 ap1 = *(const bf16x8*)&Ps[wave][lr * 72 + 32 + q4 * 8];
#pragma unroll
        for (int dt = 0; dt < 4; ++dt) {
            int vrow = dt * 16 + lr;
            bf16x8 vf0 = *(const bf16x8*)((const char*)Vs + (vrow * 8 + (q4 ^ (vrow & 7))) * 16);
            bf16x8 vf1 = *(const bf16x8*)((const char*)Vs + (vrow * 8 + ((4 + q4) ^ (vrow & 7))) * 16);
            O[dt] = mfma16(ap0, vf0, O[dt]);
            O[dt] = mfma16(ap1, vf1, O[dt]);
        }
    }

#pragma unroll
    for (int rr = 0; rr < 4; ++rr) {
        float v = lsum[rr];
        v += __shfl_xor(v, 1); v += __shfl_xor(v, 2);
        v += __shfl_xor(v, 4); v += __shfl_xor(v, 8);
        lsum[rr] = (v > 0.0f) ? (1.0f / v) : 0.0f;
    }
#pragma unroll
    for (int dt = 0; dt < 4; ++dt)
#pragma unroll
        for (int rr = 0; rr < 4; ++rr) {
            int row = n0 + wave * 16 + q4 * 4 + rr;
            att[(size_t)((b << 10) + row) * 512 + h * 64 + dt * 16 + lr] =
                (bf16)(O[dt][rr] * lsum[rr]);
        }
}

// ---------------- LayerNorms ----------------
__global__ __launch_bounds__(256) void ln1_k(const float* __restrict__ X, const float* __restrict__ R,
                                             const float* __restrict__ g, const float* __restrict__ be,
                                             float* __restrict__ O, bf16* __restrict__ Obf) {
    int row = blockIdx.x, t = threadIdx.x;
    size_t base = (size_t)row * 512;
    float t0 = X[base + t] + R[base + t];
    float t1 = X[base + 256 + t] + R[base + 256 + t];
    float s = t0 + t1, sq = t0 * t0 + t1 * t1;
#pragma unroll
    for (int off = 1; off < 64; off <<= 1) { s += __shfl_xor(s, off); sq += __shfl_xor(sq, off); }
    __shared__ float ls[4], lq[4];
    int w = t >> 6;
    if ((t & 63) == 0) { ls[w] = s; lq[w] = sq; }
    __syncthreads();
    s = ls[0] + ls[1] + ls[2] + ls[3];
    sq = lq[0] + lq[1] + lq[2] + lq[3];
    float mu = s * (1.0f / 512.0f);
    float var = sq * (1.0f / 512.0f) - mu * mu;
    float rs = rsqrtf(var + 1e-5f);
    float o0 = (t0 - mu) * rs * g[t] + be[t];
    float o1 = (t1 - mu) * rs * g[256 + t] + be[256 + t];
    O[base + t] = o0; O[base + 256 + t] = o1;
    Obf[base + t] = (bf16)o0; Obf[base + 256 + t] = (bf16)o1;
}

__global__ __launch_bounds__(256) void ln2_k(const float* __restrict__ O, const float* __restrict__ F,
                                             const float* __restrict__ g, const float* __restrict__ be,
                                             const int* __restrict__ xmask, float* __restrict__ out) {
    int row = blockIdx.x, t = threadIdx.x;
    size_t base = (size_t)row * 512;
    float t0 = O[base + t] + F[base + t];
    float t1 = O[base + 256 + t] + F[base + 256 + t];
    float s = t0 + t1, sq = t0 * t0 + t1 * t1;
#pragma unroll
    for (int off = 1; off < 64; off <<= 1) { s += __shfl_xor(s, off); sq += __shfl_xor(sq, off); }
    __shared__ float ls[4], lq[4];
    int w = t >> 6;
    if ((t & 63) == 0) { ls[w] = s; lq[w] = sq; }
    __syncthreads();
    s = ls[0] + ls[1] + ls[2] + ls[3];
    sq = lq[0] + lq[1] + lq[2] + lq[3];
    float mu = s * (1.0f / 512.0f);
    float var = sq * (1.0f / 512.0f) - mu * mu;
    float rs = rsqrtf(var + 1e-5f);
    int msk = xmask[row];
    float o0 = (t0 - mu) * rs * g[t] + be[t];
    float o1 = (t1 - mu) * rs * g[256 + t] + be[256 + t];
    out[base + t] = msk ? 0.0f : o0;
    out[base + 256 + t] = msk ? 0.0f : o1;
}

// ---------------- launcher ----------------
extern "C" void kernel_launch(void* const* d_in, const int* in_sizes, int n_in,
                              void* d_out, int out_size, void* d_ws, size_t ws_size,
                              hipStream_t stream) {
    const float* x   = (const float*)d_in[0];
    const float* y   = (const float*)d_in[1];
    const int*   xm  = (const int*)d_in[2];
    const int*   ym  = (const int*)d_in[3];
    const float* Wq  = (const float*)d_in[4];
    const float* Wk  = (const float*)d_in[5];
    const float* Wv  = (const float*)d_in[6];
    const float* Wo  = (const float*)d_in[7];
    const float* W1  = (const float*)d_in[8];
    const float* b1  = (const float*)d_in[9];
    const float* W2  = (const float*)d_in[10];
    const float* b2  = (const float*)d_in[11];
    const float* g1  = (const float*)d_in[12];
    const float* be1 = (const float*)d_in[13];
    const float* g2  = (const float*)d_in[14];
    const float* be2 = (const float*)d_in[15];

    char* ws = (char*)d_ws;
    const size_t WT_SZ  = 512 * 512 * sizeof(bf16);             // 512 KB
    const size_t XB_SZ  = (size_t)ROWS_ * 512 * sizeof(bf16);   // 8 MB
    const size_t F32_SZ = (size_t)ROWS_ * 512 * sizeof(float);  // 16 MB

    bf16* Wqt = (bf16*)(ws + 0 * WT_SZ);
    bf16* Wkt = (bf16*)(ws + 1 * WT_SZ);
    bf16* Wvt = (bf16*)(ws + 2 * WT_SZ);
    bf16* Wot = (bf16*)(ws + 3 * WT_SZ);
    bf16* W1t = (bf16*)(ws + 4 * WT_SZ);
    bf16* W2t = (bf16*)(ws + 5 * WT_SZ);
    size_t off = 6 * WT_SZ;
    bf16* Xb  = (bf16*)(ws + off); off += XB_SZ;
    bf16* Yb  = (bf16*)(ws + off); off += XB_SZ;
    bf16* qb  = (bf16*)(ws + off); off += XB_SZ;
    bf16* kb  = (bf16*)(ws + off); off += XB_SZ;
    bf16* Vt  = (bf16*)(ws + off); off += XB_SZ;
    float* awo = (float*)(ws + off); off += F32_SZ;
    float* ob  = (float*)(ws + off); off += F32_SZ;
    // reuse dead buffers:
    bf16* attb = Xb;   // Xb dead after q projection
    bf16* obf  = qb;   // qb dead after attention
    bf16* hb   = Yb;   // Yb dead after projections
    float* fb  = awo;  // awo dead after ln1

    cvt2<<<8192, 256, 0, stream>>>((const float4*)x, (const float4*)y, (bf16x4*)Xb, (bf16x4*)Yb);
    wtrans6<<<dim3(64, 6), 256, 0, stream>>>(Wq, Wk, Wv, Wo, W1, W2,
                                             Wqt, Wkt, Wvt, Wot, W1t, W2t);

    proj_qkv<<<dim3(64, 8, 3), 512, 0, stream>>>(Xb, Yb, Wqt, Wkt, Wvt, qb, kb, Vt);

    attn<<<512, 512, 0, stream>>>(qb, kb, Vt, ym, attb);

    dim3 gg(64, 8);
    gemm_bt<0><<<gg, 512, 0, stream>>>(attb, Wot, nullptr, awo);
    ln1_k<<<ROWS_, 256, 0, stream>>>(x, awo, g1, be1, ob, obf);
    gemm_bt<3><<<gg, 512, 0, stream>>>(obf, W1t, b1, hb);
    gemm_bt<2><<<gg, 512, 0, stream>>>(hb, W2t, b2, fb);
    ln2_k<<<ROWS_, 256, 0, stream>>>(ob, fb, g2, be2, xm, (float*)d_out);
}

// Round 4
// 218.176 us; speedup vs baseline: 2.3733x; 1.0307x over previous
//
#include <hip/hip_runtime.h>
#include <hip/hip_bf16.h>

typedef __bf16 bf16;
typedef __attribute__((ext_vector_type(4))) __bf16 bf16x4;
typedef __attribute__((ext_vector_type(8))) __bf16 bf16x8;
typedef __attribute__((ext_vector_type(4))) float f32x4;

#define B_ 8
#define N_ 1024
#define M_ 1024
#define H_ 8
#define ROWS_ (B_ * N_)   // 8192

__device__ __forceinline__ f32x4 mfma16(bf16x8 a, bf16x8 b, f32x4 c) {
    return __builtin_amdgcn_mfma_f32_16x16x32_bf16(a, b, c, 0, 0, 0);
}

__device__ __forceinline__ void glds16(const void* g, void* l) {
    __builtin_amdgcn_global_load_lds((const __attribute__((address_space(1))) void*)g,
                                     (__attribute__((address_space(3))) void*)l, 16, 0, 0);
}

// ---------------- prep: x/y -> bf16 (blocks 0..8191), 6 weight transposes (blocks 8192..8575) ----------------
__global__ __launch_bounds__(256) void prep(const float* __restrict__ x, const float* __restrict__ y,
                                            bf16* __restrict__ Xb, bf16* __restrict__ Yb,
                                            const float* W0, const float* W1, const float* W2,
                                            const float* W3, const float* W4, const float* W5,
                                            bf16* T0, bf16* T1, bf16* T2, bf16* T3, bf16* T4, bf16* T5) {
    __shared__ float t[64][65];
    int bid = blockIdx.x;
    if (bid < 8192) {
        int i = bid * 256 + threadIdx.x;   // float4 groups, 2M total
        const float4* s;
        bf16x4* d;
        int j;
        if (i < 1048576) { s = (const float4*)x; d = (bf16x4*)Xb; j = i; }
        else             { s = (const float4*)y; d = (bf16x4*)Yb; j = i - 1048576; }
        float4 f = s[j];
        bf16x4 o = {(bf16)f.x, (bf16)f.y, (bf16)f.z, (bf16)f.w};
        d[j] = o;
        return;
    }
    int wb = bid - 8192;                  // 0..383
    const float* srcs[6] = {W0, W1, W2, W3, W4, W5};
    bf16* dsts[6] = {T0, T1, T2, T3, T4, T5};
    const float* W = srcs[wb >> 6];
    bf16* Wt = dsts[wb >> 6];
    int tile = wb & 63;
    int k0 = (tile >> 3) * 64, n0 = (tile & 7) * 64;
    int tx = threadIdx.x & 63, ty = threadIdx.x >> 6;
#pragma unroll
    for (int j = 0; j < 16; ++j)
        t[ty + j * 4][tx] = W[(size_t)(k0 + ty + j * 4) * 512 + n0 + tx];
    __syncthreads();
#pragma unroll
    for (int j = 0; j < 16; ++j)
        Wt[(size_t)(n0 + ty + j * 4) * 512 + k0 + tx] = (bf16)t[tx][ty + j * 4];
}

// ---------------- GEMM core: 128(A-rows) x 64(Bt-rows) tile, BK=64, 4 waves ----------------
// wave owns 32 rows (2x 16-row MFMA tiles) x 64 cols. As/Bs swizzled: chunk ^= (row&7).
__device__ __forceinline__ void gemm_core(const bf16* __restrict__ A, const bf16* __restrict__ Bt,
                                          int row0, int col0, bf16* As, bf16* Bs, f32x4 acc[2][4]) {
    int tid = threadIdx.x, wave = tid >> 6, lane = tid & 63;
    int lr = lane & 15, q4 = lane >> 4;
    const bf16* Asrc[4];
    const bf16* Bsrc[2];
#pragma unroll
    for (int s = 0; s < 4; ++s) {
        int c = tid + s * 256, r = c >> 3, bk = (c & 7) ^ (r & 7);
        Asrc[s] = A + (size_t)(row0 + r) * 512 + bk * 8;
    }
#pragma unroll
    for (int s = 0; s < 2; ++s) {
        int c = tid + s * 256, r = c >> 3, bk = (c & 7) ^ (r & 7);
        Bsrc[s] = Bt + (size_t)(col0 + r) * 512 + bk * 8;
    }
    int wb = wave * 1024;
    for (int k0 = 0; k0 < 512; k0 += 64) {
        __syncthreads();
#pragma unroll
        for (int s = 0; s < 4; ++s) glds16(Asrc[s] + k0, (char*)As + s * 4096 + wb);
#pragma unroll
        for (int s = 0; s < 2; ++s) glds16(Bsrc[s] + k0, (char*)Bs + s * 4096 + wb);
        __syncthreads();
        bf16x8 af[2][2], bfr[4][2];
#pragma unroll
        for (int rt = 0; rt < 2; ++rt) {
            int row = wave * 32 + rt * 16 + lr;
#pragma unroll
            for (int c = 0; c < 2; ++c)
                af[rt][c] = *(const bf16x8*)((const char*)As + (row * 8 + ((c * 4 + q4) ^ (row & 7))) * 16);
        }
#pragma unroll
        for (int ct = 0; ct < 4; ++ct) {
            int col = ct * 16 + lr;
#pragma unroll
            for (int c = 0; c < 2; ++c)
                bfr[ct][c] = *(const bf16x8*)((const char*)Bs + (col * 8 + ((c * 4 + q4) ^ (col & 7))) * 16);
        }
#pragma unroll
        for (int rt = 0; rt < 2; ++rt)
#pragma unroll
            for (int ct = 0; ct < 4; ++ct) {
                acc[rt][ct] = mfma16(af[rt][0], bfr[ct][0], acc[rt][ct]);
                acc[rt][ct] = mfma16(af[rt][1], bfr[ct][1], acc[rt][ct]);
            }
    }
}

// fused QKV projections. z=0: q = Xb@Wq; z=1: k = Yb@Wk; z=2: Vt = (Yb@Wv)^T scattered
__global__ __launch_bounds__(256) void proj_qkv(const bf16* __restrict__ Xb, const bf16* __restrict__ Yb,
                                                const bf16* __restrict__ Wqt, const bf16* __restrict__ Wkt,
                                                const bf16* __restrict__ Wvt,
                                                bf16* __restrict__ qb, bf16* __restrict__ kb,
                                                bf16* __restrict__ Vt) {
    __shared__ bf16 As[128 * 64];
    __shared__ bf16 Bs[64 * 64];
    int z = blockIdx.z;
    const bf16 *A, *Bt;
    int row0, col0;
    if (z == 0)      { A = Xb;  Bt = Wqt; row0 = blockIdx.x * 128; col0 = blockIdx.y * 64; }
    else if (z == 1) { A = Yb;  Bt = Wkt; row0 = blockIdx.x * 128; col0 = blockIdx.y * 64; }
    else { A = Wvt; Bt = Yb; int flat = blockIdx.y * 64 + blockIdx.x; row0 = (flat & 3) * 128; col0 = (flat >> 2) * 64; }
    const f32x4 z4 = {0.f, 0.f, 0.f, 0.f};
    f32x4 acc[2][4] = {{z4, z4, z4, z4}, {z4, z4, z4, z4}};
    gemm_core(A, Bt, row0, col0, As, Bs, acc);
    int wave = threadIdx.x >> 6, lane = threadIdx.x & 63, lr = lane & 15, q4 = lane >> 4;
    bf16* dst = (z == 0) ? qb : kb;
#pragma unroll
    for (int rt = 0; rt < 2; ++rt)
#pragma unroll
        for (int ct = 0; ct < 4; ++ct) {
            int col = col0 + ct * 16 + lr;
#pragma unroll
            for (int r = 0; r < 4; ++r) {
                int row = row0 + wave * 32 + rt * 16 + q4 * 4 + r;
                bf16 v = (bf16)acc[rt][ct][r];
                if (z < 2) dst[(size_t)row * 512 + col] = v;
                else Vt[(size_t)((col >> 10) * 512 + row) * 1024 + (col & 1023)] = v;
            }
        }
}

// MODE: 0 fp32 out; 2 fp32+bias; 3 bf16+bias+relu
template <int MODE>
__global__ __launch_bounds__(256) void gemm_bt(const bf16* __restrict__ A, const bf16* __restrict__ Bt,
                                               const float* __restrict__ bias, void* __restrict__ Cout) {
    __shared__ bf16 As[128 * 64];
    __shared__ bf16 Bs[64 * 64];
    int row0 = blockIdx.x * 128, col0 = blockIdx.y * 64;
    const f32x4 z4 = {0.f, 0.f, 0.f, 0.f};
    f32x4 acc[2][4] = {{z4, z4, z4, z4}, {z4, z4, z4, z4}};
    gemm_core(A, Bt, row0, col0, As, Bs, acc);
    int wave = threadIdx.x >> 6, lane = threadIdx.x & 63, lr = lane & 15, q4 = lane >> 4;
#pragma unroll
    for (int rt = 0; rt < 2; ++rt)
#pragma unroll
        for (int ct = 0; ct < 4; ++ct) {
            int col = col0 + ct * 16 + lr;
            float bv = (MODE >= 2) ? bias[col] : 0.0f;
#pragma unroll
            for (int r = 0; r < 4; ++r) {
                int row = row0 + wave * 32 + rt * 16 + q4 * 4 + r;
                float v = acc[rt][ct][r] + bv;
                if (MODE == 3) v = fmaxf(v, 0.0f);
                if (MODE == 3) ((bf16*)Cout)[(size_t)row * 512 + col] = (bf16)v;
                else           ((float*)Cout)[(size_t)row * 512 + col] = v;
            }
        }
}

// ---------------- attention ----------------
// 512 thr (8 waves), Q-tile 128 (wave owns 16 q rows), 128-key iterations (2x 64-key halves).
// bid = n0tile*64 + (b*8+h) so same-(b,h) blocks share K/V in L2.
__global__ __launch_bounds__(512) void attn(const bf16* __restrict__ Q, const bf16* __restrict__ Kb,
                                            const bf16* __restrict__ Vt, const int* __restrict__ ymask,
                                            bf16* __restrict__ att) {
    __shared__ bf16 Ks[2][64 * 64];     // [key][d], swizzled
    __shared__ bf16 Vs[2][64 * 64];     // [d][m], swizzled
    __shared__ bf16 Ps[8][16 * 72];     // per-wave P [q][key], stride 72, reused per half

    int bid = blockIdx.x;
    int bh = bid & 63, n0 = (bid >> 6) * 128;
    int b = bh >> 3, h = bh & 7;
    int tid = threadIdx.x, wave = tid >> 6, lane = tid & 63;
    int lr = lane & 15, q4 = lane >> 4;
    const float scale = 0.044194173824159216f;   // 1/sqrt(512)

    const bf16* qp = Q + (size_t)((b << 10) + n0 + wave * 16 + lr) * 512 + h * 64 + q4 * 8;
    bf16x8 aq0 = *(const bf16x8*)qp;
    bf16x8 aq1 = *(const bf16x8*)(qp + 32);

    int r = tid >> 3, bk = (tid & 7) ^ (r & 7);
    const bf16* Ksrc = Kb + (size_t)((b << 10) + r) * 512 + h * 64 + bk * 8;
    const bf16* Vsrc = Vt + (size_t)(b * 512 + h * 64 + r) * 1024 + bk * 8;
    int wb = wave * 1024;

    const f32x4 zv = {0.f, 0.f, 0.f, 0.f};
    f32x4 O[4] = {zv, zv, zv, zv};
    float lsum[4] = {0.f, 0.f, 0.f, 0.f};

    for (int m0 = 0; m0 < M_; m0 += 128) {
        int mk0 = ymask[(b << 10) + m0 + lane];
        int mk1 = ymask[(b << 10) + m0 + 64 + lane];
        __syncthreads();
        glds16(Ksrc + (size_t)m0 * 512, (char*)Ks[0] + wb);
        glds16(Ksrc + (size_t)(m0 + 64) * 512, (char*)Ks[1] + wb);
        glds16(Vsrc + m0, (char*)Vs[0] + wb);
        glds16(Vsrc + m0 + 64, (char*)Vs[1] + wb);
        __syncthreads();

#pragma unroll
        for (int half = 0; half < 2; ++half) {
            const char* K_ = (const char*)Ks[half];
            const char* V_ = (const char*)Vs[half];
            int mkh = half ? mk1 : mk0;
#pragma unroll
            for (int nt = 0; nt < 4; ++nt) {
                int krow = nt * 16 + lr;
                bf16x8 kf0 = *(const bf16x8*)(K_ + (krow * 8 + (q4 ^ (krow & 7))) * 16);
                bf16x8 kf1 = *(const bf16x8*)(K_ + (krow * 8 + ((4 + q4) ^ (krow & 7))) * 16);
                int mkv = __shfl(mkh, krow);
                f32x4 s = mfma16(aq0, kf0, zv);
                s = mfma16(aq1, kf1, s);
#pragma unroll
                for (int rr = 0; rr < 4; ++rr) {
                    float p = mkv ? 0.0f : __expf(s[rr] * scale);
                    lsum[rr] += p;
                    Ps[wave][(q4 * 4 + rr) * 72 + krow] = (bf16)p;
                }
            }
            // per-wave in-order DS pipe: no barrier needed for Ps round-trip
            bf16x8 ap0 = *(const bf16x8*)&Ps[wave][lr * 72 + q4 * 8];
            bf16x8 ap1 = *(const bf16x8*)&Ps[wave][lr * 72 + 32 + q4 * 8];
#pragma unroll
            for (int dt = 0; dt < 4; ++dt) {
                int vrow = dt * 16 + lr;
                bf16x8 vf0 = *(const bf16x8*)(V_ + (vrow * 8 + (q4 ^ (vrow & 7))) * 16);
                bf16x8 vf1 = *(const bf16x8*)(V_ + (vrow * 8 + ((4 + q4) ^ (vrow & 7))) * 16);
                O[dt] = mfma16(ap0, vf0, O[dt]);
                O[dt] = mfma16(ap1, vf1, O[dt]);
            }
        }
    }

#pragma unroll
    for (int rr = 0; rr < 4; ++rr) {
        float v = lsum[rr];
        v += __shfl_xor(v, 1); v += __shfl_xor(v, 2);
        v += __shfl_xor(v, 4); v += __shfl_xor(v, 8);
        lsum[rr] = (v > 0.0f) ? (1.0f / v) : 0.0f;
    }
#pragma unroll
    for (int dt = 0; dt < 4; ++dt)
#pragma unroll
        for (int rr = 0; rr < 4; ++rr) {
            int row = n0 + wave * 16 + q4 * 4 + rr;
            att[(size_t)((b << 10) + row) * 512 + h * 64 + dt * 16 + lr] =
                (bf16)(O[dt][rr] * lsum[rr]);
        }
}

// ---------------- LayerNorms ----------------
__global__ __launch_bounds__(256) void ln1_k(const float* __restrict__ X, const float* __restrict__ R,
                                             const float* __restrict__ g, const float* __restrict__ be,
                                             float* __restrict__ O, bf16* __restrict__ Obf) {
    int row = blockIdx.x, t = threadIdx.x;
    size_t base = (size_t)row * 512;
    float t0 = X[base + t] + R[base + t];
    float t1 = X[base + 256 + t] + R[base + 256 + t];
    float s = t0 + t1, sq = t0 * t0 + t1 * t1;
#pragma unroll
    for (int off = 1; off < 64; off <<= 1) { s += __shfl_xor(s, off); sq += __shfl_xor(sq, off); }
    __shared__ float ls[4], lq[4];
    int w = t >> 6;
    if ((t & 63) == 0) { ls[w] = s; lq[w] = sq; }
    __syncthreads();
    s = ls[0] + ls[1] + ls[2] + ls[3];
    sq = lq[0] + lq[1] + lq[2] + lq[3];
    float mu = s * (1.0f / 512.0f);
    float var = sq * (1.0f / 512.0f) - mu * mu;
    float rs = rsqrtf(var + 1e-5f);
    float o0 = (t0 - mu) * rs * g[t] + be[t];
    float o1 = (t1 - mu) * rs * g[256 + t] + be[256 + t];
    O[base + t] = o0; O[base + 256 + t] = o1;
    Obf[base + t] = (bf16)o0; Obf[base + 256 + t] = (bf16)o1;
}

__global__ __launch_bounds__(256) void ln2_k(const float* __restrict__ O, const float* __restrict__ F,
                                             const float* __restrict__ g, const float* __restrict__ be,
                                             const int* __restrict__ xmask, float* __restrict__ out) {
    int row = blockIdx.x, t = threadIdx.x;
    size_t base = (size_t)row * 512;
    float t0 = O[base + t] + F[base + t];
    float t1 = O[base + 256 + t] + F[base + 256 + t];
    float s = t0 + t1, sq = t0 * t0 + t1 * t1;
#pragma unroll
    for (int off = 1; off < 64; off <<= 1) { s += __shfl_xor(s, off); sq += __shfl_xor(sq, off); }
    __shared__ float ls[4], lq[4];
    int w = t >> 6;
    if ((t & 63) == 0) { ls[w] = s; lq[w] = sq; }
    __syncthreads();
    s = ls[0] + ls[1] + ls[2] + ls[3];
    sq = lq[0] + lq[1] + lq[2] + lq[3];
    float mu = s * (1.0f / 512.0f);
    float var = sq * (1.0f / 512.0f) - mu * mu;
    float rs = rsqrtf(var + 1e-5f);
    int msk = xmask[row];
    float o0 = (t0 - mu) * rs * g[t] + be[t];
    float o1 = (t1 - mu) * rs * g[256 + t] + be[256 + t];
    out[base + t] = msk ? 0.0f : o0;
    out[base + 256 + t] = msk ? 0.0f : o1;
}

// ---------------- launcher ----------------
extern "C" void kernel_launch(void* const* d_in, const int* in_sizes, int n_in,
                              void* d_out, int out_size, void* d_ws, size_t ws_size,
                              hipStream_t stream) {
    const float* x   = (const float*)d_in[0];
    const float* y   = (const float*)d_in[1];
    const int*   xm  = (const int*)d_in[2];
    const int*   ym  = (const int*)d_in[3];
    const float* Wq  = (const float*)d_in[4];
    const float* Wk  = (const float*)d_in[5];
    const float* Wv  = (const float*)d_in[6];
    const float* Wo  = (const float*)d_in[7];
    const float* W1  = (const float*)d_in[8];
    const float* b1  = (const float*)d_in[9];
    const float* W2  = (const float*)d_in[10];
    const float* b2  = (const float*)d_in[11];
    const float* g1  = (const float*)d_in[12];
    const float* be1 = (const float*)d_in[13];
    const float* g2  = (const float*)d_in[14];
    const float* be2 = (const float*)d_in[15];

    char* ws = (char*)d_ws;
    const size_t WT_SZ  = 512 * 512 * sizeof(bf16);             // 512 KB
    const size_t XB_SZ  = (size_t)ROWS_ * 512 * sizeof(bf16);   // 8 MB
    const size_t F32_SZ = (size_t)ROWS_ * 512 * sizeof(float);  // 16 MB

    bf16* Wqt = (bf16*)(ws + 0 * WT_SZ);
    bf16* Wkt = (bf16*)(ws + 1 * WT_SZ);
    bf16* Wvt = (bf16*)(ws + 2 * WT_SZ);
    bf16* Wot = (bf16*)(ws + 3 * WT_SZ);
    bf16* W1t = (bf16*)(ws + 4 * WT_SZ);
    bf16* W2t = (bf16*)(ws + 5 * WT_SZ);
    size_t off = 6 * WT_SZ;
    bf16* Xb  = (bf16*)(ws + off); off += XB_SZ;
    bf16* Yb  = (bf16*)(ws + off); off += XB_SZ;
    bf16* qb  = (bf16*)(ws + off); off += XB_SZ;
    bf16* kb  = (bf16*)(ws + off); off += XB_SZ;
    bf16* Vt  = (bf16*)(ws + off); off += XB_SZ;
    float* awo = (float*)(ws + off); off += F32_SZ;
    float* ob  = (float*)(ws + off); off += F32_SZ;
    // reuse dead buffers:
    bf16* attb = Xb;   // Xb dead after q projection
    bf16* obf  = qb;   // qb dead after attention
    bf16* hb   = Yb;   // Yb dead after projections
    float* fb  = awo;  // awo dead after ln1

    prep<<<8576, 256, 0, stream>>>(x, y, Xb, Yb, Wq, Wk, Wv, Wo, W1, W2,
                                   Wqt, Wkt, Wvt, Wot, W1t, W2t);

    proj_qkv<<<dim3(64, 8, 3), 256, 0, stream>>>(Xb, Yb, Wqt, Wkt, Wvt, qb, kb, Vt);

    attn<<<512, 512, 0, stream>>>(qb, kb, Vt, ym, attb);

    dim3 gg(64, 8);
    gemm_bt<0><<<gg, 256, 0, stream>>>(attb, Wot, nullptr, awo);
    ln1_k<<<ROWS_, 256, 0, stream>>>(x, awo, g1, be1, ob, obf);
    gemm_bt<3><<<gg, 256, 0, stream>>>(obf, W1t, b1, hb);
    gemm_bt<2><<<gg, 256, 0, stream>>>(hb, W2t, b2, fb);
    ln2_k<<<ROWS_, 256, 0, stream>>>(ob, fb, g2, be2, xm, (float*)d_out);
}